// Round 11
// baseline (273.227 us; speedup 1.0000x reference)
//
#include <hip/hip_runtime.h>
#include <hip/hip_bf16.h>
#include <cstddef>
#include <cstdint>

#define Bn 4
#define Tn 2048
#define Cn 1024
#define Hn 16
#define Rn 256
static constexpr float SCALE = 0.125f; // 1/sqrt(64)

typedef __attribute__((ext_vector_type(8))) short bf16x8;  // 8 bf16 (4 VGPRs)
typedef __attribute__((ext_vector_type(4))) short bf16x4;  // 8 B
typedef __attribute__((ext_vector_type(4))) float f32x4;

__device__ inline short f2bf(float v) {
  return __builtin_bit_cast(short, __float2bfloat16(v));
}
__device__ inline float bf2f(short s) {
  return __builtin_bit_cast(float, (unsigned)(unsigned short)s << 16);
}
// native 2^x (v_exp_f32); exp2f lowers to the slow ocml path (r2 post-mortem)
__device__ inline float fexp2(float x) {
  float r;
  asm("v_exp_f32 %0, %1" : "=v"(r) : "v"(x));
  return r;
}

// async global->LDS, 16 B per lane; LDS dst = wave-uniform base + lane*16
__device__ inline void gld16(const short* g, short* l) {
  __builtin_amdgcn_global_load_lds(
      (const __attribute__((address_space(1))) unsigned*)g,
      (__attribute__((address_space(3))) unsigned*)l, 16, 0, 0);
}

// ---------------------------------------------------------------------------
// Fused fp32->bf16 convert for x|basis|vproj|oproj (contiguous dst in ws)
// + uv pack: u,v [H,R,S] -> uvb [H,128,R] (transposed, q|k concat).
// U is pre-scaled by SCALE*log2(e) so attention can use exp2 directly.
// ---------------------------------------------------------------------------
#define NCVT 1343488  // 8-elem units: x 1048576 | basis 32768 | vp 131072 | op 131072
__global__ __launch_bounds__(256) void cvtall(
    const float* __restrict__ x, const float* __restrict__ basis,
    const float* __restrict__ vproj, const float* __restrict__ oproj,
    const float* __restrict__ U, const float* __restrict__ V,
    short* __restrict__ dst, short* __restrict__ uvb) {
  int gid = blockIdx.x * 256 + threadIdx.x;
  if (gid < NCVT) {
    const float* src;
    int off;
    if (gid < 1048576) { src = x; off = gid; }
    else if (gid < 1081344) { src = basis; off = gid - 1048576; }
    else if (gid < 1212416) { src = vproj; off = gid - 1081344; }
    else { src = oproj; off = gid - 1212416; }
    const float4* p = (const float4*)src + (size_t)off * 2;
    float4 a = p[0], b = p[1];
    bf16x8 o;
    o[0] = f2bf(a.x); o[1] = f2bf(a.y); o[2] = f2bf(a.z); o[3] = f2bf(a.w);
    o[4] = f2bf(b.x); o[5] = f2bf(b.y); o[6] = f2bf(b.z); o[7] = f2bf(b.w);
    *((bf16x8*)dst + gid) = o;
  } else if (gid < NCVT + 65536) {
    int base = (gid - NCVT) * 8;
    int r0 = base & 255, j = (base >> 8) & 127, h = base >> 15;
    // SCALE * log2(e) folded into U (U only feeds Q)
    const float QS = 0.18033688f;
    bf16x8 o;
#pragma unroll
    for (int i = 0; i < 8; ++i) {
      int r = r0 + i;
      float v = (j < 64) ? U[((size_t)h * 256 + r) * 64 + j] * QS
                         : V[((size_t)h * 256 + r) * 64 + (j - 64)];
      o[i] = f2bf(v);
    }
    *(bf16x8*)(uvb + base) = o;
  }
}

// ---------------------------------------------------------------------------
// bf16 MFMA GEMM, 2-phase double-buffered (r10): stage tile k+1 BEFORE
// computing tile k; ONE __syncthreads per K-step. 128x128 tile, BK=32,
// 4 waves (2x2 of 64x64), LDS 32 KB.
// SMODE 3: fp32 C0[m*N+n]
// SMODE 5: fused latent|V^T: n<256 -> latent bf16 [m,256] in C0 (no bias);
//          n>=256 -> V^T [bh][d][t] packed bf16x4 in C1 (+v_proj bias).
// SMODE 6: swapped q|k: A=uvb (m = h*128+dd), B=latentb (n = t row).
//          acc r-group = 4 consecutive dd -> ONE bf16x4 store into
//          Q[bh][t][d] (dd<64, C0) or K[bh][t][d] (dd>=64, C1).
//          (r11: replaces SMODE1's 64 scalar 2B stores with 16 vector 8B)
// ---------------------------------------------------------------------------
template <int SMODE, int BIAS>
__global__ __launch_bounds__(256) void gemm_mfma(
    const short* __restrict__ A, const short* __restrict__ Bm,
    const float* __restrict__ bias, void* __restrict__ C0,
    void* __restrict__ C1, int M, int N, int K, int bstride) {
  __shared__ short As[2][128 * 32];
  __shared__ short Bs[2][128 * 32];
  const int tid = threadIdx.x;
  const int lane = tid & 63, l16 = lane & 15, quad = lane >> 4;
  const int wave = tid >> 6;
  const int wm = (wave >> 1) * 64, wn = (wave & 1) * 64;
  const int m0 = blockIdx.x * 128, n0 = blockIdx.y * 128;
  const short* Bp = Bm + (size_t)blockIdx.z * bstride;

  f32x4 acc[4][4];
#pragma unroll
  for (int i = 0; i < 4; ++i)
#pragma unroll
    for (int j = 0; j < 4; ++j) acc[i][j] = f32x4{0.f, 0.f, 0.f, 0.f};

  const int arow = tid >> 2, achk = (tid & 3) * 8;
#define GSTAGE(buf, kk)                                                       \
  {                                                                           \
    gld16(A + (size_t)(m0 + arow) * K + (kk) + achk, &As[buf][tid * 8]);      \
    gld16(A + (size_t)(m0 + 64 + arow) * K + (kk) + achk,                     \
          &As[buf][2048 + tid * 8]);                                          \
    gld16(Bp + (size_t)(n0 + arow) * K + (kk) + achk, &Bs[buf][tid * 8]);     \
    gld16(Bp + (size_t)(n0 + 64 + arow) * K + (kk) + achk,                    \
          &Bs[buf][2048 + tid * 8]);                                          \
  }

  GSTAGE(0, 0);
  __syncthreads();  // prologue: buf0 ready
  int cur = 0;
  for (int k0 = 0; k0 < K; k0 += 32) {
    if (k0 + 32 < K) GSTAGE(cur ^ 1, k0 + 32);  // hidden under MFMA below
    bf16x8 af[4], bf[4];
#pragma unroll
    for (int i = 0; i < 4; ++i)
      af[i] = *(const bf16x8*)&As[cur][(wm + i * 16 + l16) * 32 + quad * 8];
#pragma unroll
    for (int j = 0; j < 4; ++j)
      bf[j] = *(const bf16x8*)&Bs[cur][(wn + j * 16 + l16) * 32 + quad * 8];
#pragma unroll
    for (int i = 0; i < 4; ++i)
#pragma unroll
      for (int j = 0; j < 4; ++j)
        acc[i][j] =
            __builtin_amdgcn_mfma_f32_16x16x32_bf16(af[i], bf[j], acc[i][j], 0, 0, 0);
    __syncthreads();  // drains stage(k+1); all waves done reading buf[cur]
    cur ^= 1;
  }

  if (SMODE == 6) {
    // swapped q|k epilogue: m = h*128 + dd, n = global t row.
    const int h = m0 >> 7;
#pragma unroll
    for (int i = 0; i < 4; ++i) {
      int dd = wm + i * 16 + quad * 4;      // wave-uniform q/k branch (wm)
      short* qk = (short*)(dd < 64 ? C0 : C1);
      int dcol = dd & 63;
#pragma unroll
      for (int j = 0; j < 4; ++j) {
        int n = n0 + wn + j * 16 + l16;
        int b = n >> 11, t = n & 2047;
        bf16x4 pk;
#pragma unroll
        for (int r = 0; r < 4; ++r) pk[r] = f2bf(acc[i][j][r]);
        *(bf16x4*)(qk + ((size_t)(b * Hn + h) * Tn + t) * 64 + dcol) = pk;
      }
    }
    return;
  }

  float bj[4];
#pragma unroll
  for (int j = 0; j < 4; ++j) {
    if (SMODE == 5)
      bj[j] = (n0 >= 256) ? bias[(n0 - 256) + wn + j * 16 + l16] : 0.f;
    else
      bj[j] = BIAS ? bias[n0 + wn + j * 16 + l16] : 0.f;
  }

  if (SMODE == 5 && n0 >= 256) {
    // V^T direct: [bh][d][t]; t = m0+wm+i*16+quad*4+r, d = j*16+l16,
    // h = (n0+wn-256)>>6. 4 consecutive t -> one 8B store.
    const int h = (n0 + wn - 256) >> 6;
#pragma unroll
    for (int i = 0; i < 4; ++i) {
      int m = m0 + wm + i * 16 + quad * 4;
      int b = m >> 11, t0 = m & 2047;
#pragma unroll
      for (int j = 0; j < 4; ++j) {
        int d = j * 16 + l16;
        bf16x4 pk;
#pragma unroll
        for (int r = 0; r < 4; ++r) pk[r] = f2bf(acc[i][j][r] + bj[j]);
        *(bf16x4*)((short*)C1 + ((size_t)((b * Hn + h) * 64 + d)) * Tn + t0) = pk;
      }
    }
    return;
  }

#pragma unroll
  for (int i = 0; i < 4; ++i) {
#pragma unroll
    for (int r = 0; r < 4; ++r) {
      int m = m0 + wm + i * 16 + quad * 4 + r;
#pragma unroll
      for (int j = 0; j < 4; ++j) {
        int n = n0 + wn + j * 16 + l16;
        float val = acc[i][j][r] + bj[j];
        if (SMODE == 5) {
          ((short*)C0)[(size_t)m * 256 + n] = f2bf(val);  // latent, stride 256
        } else {
          ((float*)C0)[(size_t)m * N + n] = val;
        }
      }
    }
  }
}

// ---------------------------------------------------------------------------
// MFMA flash attention v9 (FROZEN — verified 91.3 us; r4/r6/r8/r9 all lost):
// swapped QK^T (S^T = mfma(K,Q)), native v_exp_f32, P spill via 8B
// ds_write_b64, K/V LDS dbuf (tile shared once per block), ONE barrier/iter
// with stage issued right after it (a full iteration to land).
// ---------------------------------------------------------------------------
__constant__ unsigned char ORD6[12] = {12, 30, 31, 26, 27, 8,
                                       22, 23, 18, 19, 4, 0};
#define PP 72
__global__ __launch_bounds__(512) void atn9(
    const short* __restrict__ Qg, const short* __restrict__ Kg,
    const short* __restrict__ VTg, short* __restrict__ Yb,
    short* __restrict__ Opart, float* __restrict__ Lpart) {
  __shared__ short Ks[2][64 * 64];
  __shared__ short Vt[2][64 * 64];
  __shared__ short Ps[8 * 16 * PP];

  const int tid = threadIdx.x;
  const int wave = tid >> 6, lane = tid & 63;
  const int l16 = lane & 15, quad = lane >> 4;
  const unsigned v = ORD6[blockIdx.y];
  const int qt = v >> 2, split = (v >> 1) & 1, half = v & 1;
  const int bh = blockIdx.x;
  const int wtrow = qt * 256 + wave * 32;
  const size_t kb = (size_t)bh * Tn * 64;
  const size_t vb = (size_t)bh * 64 * Tn;
  const int j0 = split ? half * (2 * qt + 2) : 0;
  const int jn = split ? (2 * qt + 2) : (4 * qt + 4);

  // Q fragments: 2 row-groups x 2 k-steps
  bf16x8 qf[2][2];
#pragma unroll
  for (int rg = 0; rg < 2; ++rg)
#pragma unroll
    for (int s = 0; s < 2; ++s)
      qf[rg][s] = *(const bf16x8*)(Qg + kb +
          (size_t)(wtrow + rg * 16 + l16) * 64 + s * 32 + quad * 8);

  f32x4 o[2][4];
#pragma unroll
  for (int rg = 0; rg < 2; ++rg)
#pragma unroll
    for (int dt = 0; dt < 4; ++dt) o[rg][dt] = f32x4{0.f, 0.f, 0.f, 0.f};
  // per-lane partial row-sums for q = l16 (4 accumulators for ILP)
  float lp[2][4] = {{0.f, 0.f, 0.f, 0.f}, {0.f, 0.f, 0.f, 0.f}};

  // staging: 512 threads x 16B = one 64x64 bf16 tile per buffer per issue
  const int srow = tid >> 3;                  // 0..63
  const int sseg = (tid & 7) ^ (srow & 7);    // XOR chunk swizzle
#define STAGE7(buf, j)                                                        \
  {                                                                           \
    gld16(Kg + kb + (size_t)((j) * 64 + srow) * 64 + sseg * 8,                \
          &Ks[buf][tid * 8]);                                                 \
    gld16(VTg + vb + (size_t)srow * Tn + (j) * 64 + sseg * 8,                 \
          &Vt[buf][tid * 8]);                                                 \
  }

  STAGE7(0, j0);
  short* pw = &Ps[wave * 16 * PP];
  const int xs = l16 & 7;

  for (int jj = 0; jj < jn; ++jj) {
    const int j = j0 + jj;
    const int cb = jj & 1;
    __syncthreads();  // buf[cb] staged; all waves done reading buf[cb^1]
    if (jj + 1 < jn) STAGE7(cb ^ 1, j + 1);  // full-iteration prefetch window

    const bool act1 = (j * 64 <= wtrow + 31);
    const bool act0 = (j * 64 <= wtrow + 15);
    if (!act1) continue;  // wave still hits next barrier

    // QK^T swapped: sa[rg][ct] = S^T tile, lane holds q=l16, k=quad*4+r
    f32x4 sa[2][4];
    __builtin_amdgcn_s_setprio(1);
#pragma unroll
    for (int ct = 0; ct < 4; ++ct) {
      bf16x8 k0 = *(const bf16x8*)&Ks[cb][(ct * 16 + l16) * 64 + ((0 + quad) ^ xs) * 8];
      bf16x8 k1 = *(const bf16x8*)&Ks[cb][(ct * 16 + l16) * 64 + ((4 + quad) ^ xs) * 8];
#pragma unroll
      for (int rg = 0; rg < 2; ++rg) {
        if (rg == 0 && !act0) continue;
        f32x4 t = f32x4{0.f, 0.f, 0.f, 0.f};
        t = __builtin_amdgcn_mfma_f32_16x16x32_bf16(k0, qf[rg][0], t, 0, 0, 0);
        t = __builtin_amdgcn_mfma_f32_16x16x32_bf16(k1, qf[rg][1], t, 0, 0, 0);
        sa[rg][ct] = t;
      }
    }
    __builtin_amdgcn_s_setprio(0);

#pragma unroll
    for (int rg = 0; rg < 2; ++rg) {
      if (rg == 0 && !act0) continue;
      const int rbase = wtrow + rg * 16;
      const int trow = rbase + l16;  // this lane's q row
      const bool full = (j * 64 + 63 <= rbase);
#pragma unroll
      for (int ct = 0; ct < 4; ++ct) {
        const int ubase = j * 64 + ct * 16 + quad * 4;
        bf16x4 pk;
#pragma unroll
        for (int r = 0; r < 4; ++r) {
          float e;
          if (full) {
            e = fexp2(sa[rg][ct][r]);
          } else {
            e = (ubase + r <= trow) ? fexp2(sa[rg][ct][r]) : 0.f;
          }
          lp[rg][r] += e;
          pk[r] = f2bf(e);
        }
        *(bf16x4*)&pw[l16 * PP + ct * 16 + quad * 4] = pk;  // 8B store
      }
      bf16x8 pf0 = *(const bf16x8*)&pw[l16 * PP + quad * 8];
      bf16x8 pf1 = *(const bf16x8*)&pw[l16 * PP + 32 + quad * 8];
      // PV: load V^T frags per-dt (short live range)
      __builtin_amdgcn_s_setprio(1);
#pragma unroll
      for (int dt = 0; dt < 4; ++dt) {
        bf16x8 v0 = *(const bf16x8*)&Vt[cb][(dt * 16 + l16) * 64 + ((0 + quad) ^ xs) * 8];
        bf16x8 v1 = *(const bf16x8*)&Vt[cb][(dt * 16 + l16) * 64 + ((4 + quad) ^ xs) * 8];
        o[rg][dt] = __builtin_amdgcn_mfma_f32_16x16x32_bf16(pf0, v0, o[rg][dt], 0, 0, 0);
        o[rg][dt] = __builtin_amdgcn_mfma_f32_16x16x32_bf16(pf1, v1, o[rg][dt], 0, 0, 0);
      }
      __builtin_amdgcn_s_setprio(0);
    }
  }

  const int row = lane >> 2, cseg = lane & 3;
  if (!split) {
    const int b = bh >> 4, h = bh & 15;
#pragma unroll
    for (int rg = 0; rg < 2; ++rg) {
      // full row-sum for q=l16: combine 4 partials, then sum across quads
      float lfull = (lp[rg][0] + lp[rg][1]) + (lp[rg][2] + lp[rg][3]);
      lfull += __shfl_xor(lfull, 16);
      lfull += __shfl_xor(lfull, 32);
      float invf = 1.f / lfull;  // valid per lane for q = l16
      float inv[4];
#pragma unroll
      for (int r = 0; r < 4; ++r) inv[r] = __shfl(invf, quad * 4 + r);
#pragma unroll
      for (int dt = 0; dt < 4; ++dt)
#pragma unroll
        for (int r = 0; r < 4; ++r)
          pw[(quad * 4 + r) * PP + dt * 16 + l16] = f2bf(o[rg][dt][r] * inv[r]);
      bf16x8 y0 = *(const bf16x8*)&pw[row * PP + cseg * 16];
      bf16x8 y1 = *(const bf16x8*)&pw[row * PP + cseg * 16 + 8];
      short* dst = Yb + ((size_t)(b * Tn + wtrow + rg * 16 + row)) * Cn +
                   h * 64 + cseg * 16;
      *(bf16x8*)dst = y0;
      *(bf16x8*)(dst + 8) = y1;
    }
  } else {
    // unnormalized additive partials
    const int slot = (bh * 4 + (qt - 4)) * 2 + half;
#pragma unroll
    for (int rg = 0; rg < 2; ++rg) {
      float lfull = (lp[rg][0] + lp[rg][1]) + (lp[rg][2] + lp[rg][3]);
      lfull += __shfl_xor(lfull, 16);
      lfull += __shfl_xor(lfull, 32);
#pragma unroll
      for (int dt = 0; dt < 4; ++dt)
#pragma unroll
        for (int r = 0; r < 4; ++r)
          pw[(quad * 4 + r) * PP + dt * 16 + l16] = f2bf(o[rg][dt][r]);
      bf16x8 y0 = *(const bf16x8*)&pw[row * PP + cseg * 16];
      bf16x8 y1 = *(const bf16x8*)&pw[row * PP + cseg * 16 + 8];
      const int rrow = wave * 32 + rg * 16 + row;
      short* dst = Opart + ((size_t)slot * 256 + rrow) * 64 + cseg * 16;
      *(bf16x8*)dst = y0;
      *(bf16x8*)(dst + 8) = y1;
      if (quad == 0) Lpart[slot * 256 + wave * 32 + rg * 16 + l16] = lfull;
    }
  }
}

// ---------------------------------------------------------------------------
// combine: for qt 4..7 (rows 1024..2047), y = (Oa + Ob) / (la + lb) -> yb
// ---------------------------------------------------------------------------
__global__ __launch_bounds__(256) void combine_k(
    const short* __restrict__ Opart, const float* __restrict__ Lpart,
    short* __restrict__ Yb) {
  int gid = blockIdx.x * 256 + threadIdx.x;  // 524288
  int seg = gid & 7, row = (gid >> 3) & 255, qtr = (gid >> 11) & 3,
      bh = gid >> 13;
  int slotA = (bh * 4 + qtr) * 2, slotB = slotA + 1;
  float la = Lpart[slotA * 256 + row], lb = Lpart[slotB * 256 + row];
  float inv = 1.f / (la + lb);
  bf16x8 a = *(const bf16x8*)(Opart + ((size_t)slotA * 256 + row) * 64 + seg * 8);
  bf16x8 b = *(const bf16x8*)(Opart + ((size_t)slotB * 256 + row) * 64 + seg * 8);
  bf16x8 y;
#pragma unroll
  for (int i = 0; i < 8; ++i) y[i] = f2bf((bf2f(a[i]) + bf2f(b[i])) * inv);
  int t = (qtr + 4) * 256 + row, bb = bh >> 4, h = bh & 15;
  *(bf16x8*)(Yb + ((size_t)(bb * Tn + t)) * Cn + h * 64 + seg * 8) = y;
}

// ---------------------------------------------------------------------------
extern "C" void kernel_launch(void* const* d_in, const int* in_sizes, int n_in,
                              void* d_out, int out_size, void* d_ws,
                              size_t ws_size, hipStream_t stream) {
  const float* x        = (const float*)d_in[0];
  const float* basis_w  = (const float*)d_in[1];
  const float* u_factor = (const float*)d_in[2];
  const float* v_factor = (const float*)d_in[3];
  const float* v_proj_w = (const float*)d_in[4];
  const float* v_proj_b = (const float*)d_in[5];
  const float* o_proj_w = (const float*)d_in[6];
  const float* o_proj_b = (const float*)d_in[7];
  float* out = (float*)d_out;

  char* ws = (char*)d_ws;
  const size_t NX = (size_t)Bn * Tn * Cn;          // 8,388,608
  short* xb      = (short*)ws; ws += NX * 2;       // contig with next 3 (cvtall)
  short* bwb     = (short*)ws; ws += (size_t)Rn * Cn * 2;  // basis | vproj
  short* vpb     = (short*)ws; ws += (size_t)Cn * Cn * 2;  //   contiguous !
  short* opb     = (short*)ws; ws += (size_t)Cn * Cn * 2;
  short* uvb     = (short*)ws; ws += (size_t)Hn * 128 * Rn * 2;
  short* latentb = (short*)ws; ws += (size_t)Bn * Tn * Rn * 2;
  short* Qb      = (short*)ws; ws += NX * 2;       // [bh,T,64]
  short* Kb      = (short*)ws; ws += NX * 2;
  short* VTb     = (short*)ws; ws += NX * 2;       // [bh,64,T]
  short* yb      = (short*)ws; ws += NX * 2;       // [8192,1024]
  short* Opart   = (short*)ws; ws += (size_t)512 * 256 * 64 * 2;  // 16.8 MB
  float* Lpart   = (float*)ws;                     // 512*256 f32
  (void)vpb;

  dim3 blk(256);
  cvtall<<<dim3(5504), blk, 0, stream>>>(x, basis_w, v_proj_w, o_proj_w,
                                         u_factor, v_factor, xb, uvb);

  // fused latent|V: [8192,1280] = xb @ [basis_w;v_proj_w]^T
  //   n<256 -> latentb (bf16 [8192,256]); n>=256 -> V^T [bh,64,T] + bias
  gemm_mfma<5, 1><<<dim3(64, 10, 1), blk, 0, stream>>>(
      xb, bwb, v_proj_b, latentb, VTb, 8192, 1280, 1024, 0);
  // (q|k)^T = uvb @ latent^T, swapped operands: vectorized epilogue into
  // Q[bh][t][d] / K[bh][t][d]. grid: 16 m-blocks (heads) x 64 n-blocks (t).
  gemm_mfma<6, 0><<<dim3(16, 64, 1), blk, 0, stream>>>(
      uvb, latentb, nullptr, Qb, Kb, 2048, 8192, 256, 0);
  // attention (256-row blocks, dbuf staging, split-key) -> yb + partials
  atn9<<<dim3(64, 12), dim3(512), 0, stream>>>(Qb, Kb, VTb, yb, Opart, Lpart);
  combine_k<<<dim3(2048), blk, 0, stream>>>(Opart, Lpart, yb);
  // out = yb @ o_proj^T + b : fp32
  gemm_mfma<3, 1><<<dim3(64, 8, 1), blk, 0, stream>>>(
      yb, opb, o_proj_b, out, nullptr, 8192, 1024, 1024, 0);
}

// Round 12
// 236.523 us; speedup vs baseline: 1.1552x; 1.1552x over previous
//
#include <hip/hip_runtime.h>
#include <hip/hip_bf16.h>
#include <cstddef>
#include <cstdint>

#define Bn 4
#define Tn 2048
#define Cn 1024
#define Hn 16
#define Rn 256

typedef __attribute__((ext_vector_type(8))) short bf16x8;  // 8 bf16 (4 VGPRs)
typedef __attribute__((ext_vector_type(4))) short bf16x4;  // 8 B
typedef __attribute__((ext_vector_type(4))) float f32x4;

__device__ inline short f2bf(float v) {
  return __builtin_bit_cast(short, __float2bfloat16(v));
}
__device__ inline float bf2f(short s) {
  return __builtin_bit_cast(float, (unsigned)(unsigned short)s << 16);
}
// native 2^x (v_exp_f32); exp2f lowers to the slow ocml path (r2 post-mortem)
__device__ inline float fexp2(float x) {
  float r;
  asm("v_exp_f32 %0, %1" : "=v"(r) : "v"(x));
  return r;
}

// async global->LDS, 16 B per lane; LDS dst = wave-uniform base + lane*16
__device__ inline void gld16(const short* g, short* l) {
  __builtin_amdgcn_global_load_lds(
      (const __attribute__((address_space(1))) unsigned*)g,
      (__attribute__((address_space(3))) unsigned*)l, 16, 0, 0);
}

// ---------------------------------------------------------------------------
// Fused fp32->bf16 convert for x|basis|vproj|oproj (contiguous dst in ws)
// + uv pack: u,v [H,R,S] -> uvb [H,128,R] (transposed, q|k concat).
// U is pre-scaled by SCALE*log2(e) so attention can use exp2 directly.
// ---------------------------------------------------------------------------
#define NCVT 1343488  // 8-elem units: x 1048576 | basis 32768 | vp 131072 | op 131072
__global__ __launch_bounds__(256) void cvtall(
    const float* __restrict__ x, const float* __restrict__ basis,
    const float* __restrict__ vproj, const float* __restrict__ oproj,
    const float* __restrict__ U, const float* __restrict__ V,
    short* __restrict__ dst, short* __restrict__ uvb) {
  int gid = blockIdx.x * 256 + threadIdx.x;
  if (gid < NCVT) {
    const float* src;
    int off;
    if (gid < 1048576) { src = x; off = gid; }
    else if (gid < 1081344) { src = basis; off = gid - 1048576; }
    else if (gid < 1212416) { src = vproj; off = gid - 1081344; }
    else { src = oproj; off = gid - 1212416; }
    const float4* p = (const float4*)src + (size_t)off * 2;
    float4 a = p[0], b = p[1];
    bf16x8 o;
    o[0] = f2bf(a.x); o[1] = f2bf(a.y); o[2] = f2bf(a.z); o[3] = f2bf(a.w);
    o[4] = f2bf(b.x); o[5] = f2bf(b.y); o[6] = f2bf(b.z); o[7] = f2bf(b.w);
    *((bf16x8*)dst + gid) = o;
  } else if (gid < NCVT + 65536) {
    int base = (gid - NCVT) * 8;
    int r0 = base & 255, j = (base >> 8) & 127, h = base >> 15;
    // SCALE * log2(e) folded into U (U only feeds Q)
    const float QS = 0.18033688f;
    bf16x8 o;
#pragma unroll
    for (int i = 0; i < 8; ++i) {
      int r = r0 + i;
      float v = (j < 64) ? U[((size_t)h * 256 + r) * 64 + j] * QS
                         : V[((size_t)h * 256 + r) * 64 + (j - 64)];
      o[i] = f2bf(v);
    }
    *(bf16x8*)(uvb + base) = o;
  }
}

// ---------------------------------------------------------------------------
// bf16 MFMA GEMM, 2-phase double-buffered (r10): stage tile k+1 BEFORE
// computing tile k; ONE __syncthreads per K-step. 128x128 tile, BK=32,
// 4 waves (2x2 of 64x64), LDS 32 KB.
// SMODE 1: per-head q|k split (blockIdx.z=h, N=128)   [r11 swap reverted]
// SMODE 3: fp32 C0[m*N+n]
// SMODE 5: fused latent|V^T: n<256 -> latent bf16 [m,256] in C0 (no bias);
//          n>=256 -> V^T [bh][d][t] packed bf16x4 in C1 (+v_proj bias).
// ---------------------------------------------------------------------------
template <int SMODE, int BIAS>
__global__ __launch_bounds__(256) void gemm_mfma(
    const short* __restrict__ A, const short* __restrict__ Bm,
    const float* __restrict__ bias, void* __restrict__ C0,
    void* __restrict__ C1, int M, int N, int K, int bstride) {
  __shared__ short As[2][128 * 32];
  __shared__ short Bs[2][128 * 32];
  const int tid = threadIdx.x;
  const int lane = tid & 63, l16 = lane & 15, quad = lane >> 4;
  const int wave = tid >> 6;
  const int wm = (wave >> 1) * 64, wn = (wave & 1) * 64;
  const int m0 = blockIdx.x * 128, n0 = blockIdx.y * 128;
  const short* Bp = Bm + (size_t)blockIdx.z * bstride;

  f32x4 acc[4][4];
#pragma unroll
  for (int i = 0; i < 4; ++i)
#pragma unroll
    for (int j = 0; j < 4; ++j) acc[i][j] = f32x4{0.f, 0.f, 0.f, 0.f};

  const int arow = tid >> 2, achk = (tid & 3) * 8;
#define GSTAGE(buf, kk)                                                       \
  {                                                                           \
    gld16(A + (size_t)(m0 + arow) * K + (kk) + achk, &As[buf][tid * 8]);      \
    gld16(A + (size_t)(m0 + 64 + arow) * K + (kk) + achk,                     \
          &As[buf][2048 + tid * 8]);                                          \
    gld16(Bp + (size_t)(n0 + arow) * K + (kk) + achk, &Bs[buf][tid * 8]);     \
    gld16(Bp + (size_t)(n0 + 64 + arow) * K + (kk) + achk,                    \
          &Bs[buf][2048 + tid * 8]);                                          \
  }

  GSTAGE(0, 0);
  __syncthreads();  // prologue: buf0 ready
  int cur = 0;
  for (int k0 = 0; k0 < K; k0 += 32) {
    if (k0 + 32 < K) GSTAGE(cur ^ 1, k0 + 32);  // hidden under MFMA below
    bf16x8 af[4], bf[4];
#pragma unroll
    for (int i = 0; i < 4; ++i)
      af[i] = *(const bf16x8*)&As[cur][(wm + i * 16 + l16) * 32 + quad * 8];
#pragma unroll
    for (int j = 0; j < 4; ++j)
      bf[j] = *(const bf16x8*)&Bs[cur][(wn + j * 16 + l16) * 32 + quad * 8];
#pragma unroll
    for (int i = 0; i < 4; ++i)
#pragma unroll
      for (int j = 0; j < 4; ++j)
        acc[i][j] =
            __builtin_amdgcn_mfma_f32_16x16x32_bf16(af[i], bf[j], acc[i][j], 0, 0, 0);
    __syncthreads();  // drains stage(k+1); all waves done reading buf[cur]
    cur ^= 1;
  }

  float bj[4];
#pragma unroll
  for (int j = 0; j < 4; ++j) {
    if (SMODE == 5)
      bj[j] = (n0 >= 256) ? bias[(n0 - 256) + wn + j * 16 + l16] : 0.f;
    else
      bj[j] = BIAS ? bias[n0 + wn + j * 16 + l16] : 0.f;
  }

  if (SMODE == 5 && n0 >= 256) {
    // V^T direct: [bh][d][t]; t = m0+wm+i*16+quad*4+r, d = j*16+l16,
    // h = (n0+wn-256)>>6. 4 consecutive t -> one 8B store.
    const int h = (n0 + wn - 256) >> 6;
#pragma unroll
    for (int i = 0; i < 4; ++i) {
      int m = m0 + wm + i * 16 + quad * 4;
      int b = m >> 11, t0 = m & 2047;
#pragma unroll
      for (int j = 0; j < 4; ++j) {
        int d = j * 16 + l16;
        bf16x4 pk;
#pragma unroll
        for (int r = 0; r < 4; ++r) pk[r] = f2bf(acc[i][j][r] + bj[j]);
        *(bf16x4*)((short*)C1 + ((size_t)((b * Hn + h) * 64 + d)) * Tn + t0) = pk;
      }
    }
    return;
  }

#pragma unroll
  for (int i = 0; i < 4; ++i) {
#pragma unroll
    for (int r = 0; r < 4; ++r) {
      int m = m0 + wm + i * 16 + quad * 4 + r;
      int b = m >> 11, t = m & 2047;
#pragma unroll
      for (int j = 0; j < 4; ++j) {
        int n = n0 + wn + j * 16 + l16;
        float val = acc[i][j][r] + bj[j];
        if (SMODE == 5) {
          ((short*)C0)[(size_t)m * 256 + n] = f2bf(val);  // latent, stride 256
        } else if (SMODE == 1) {
          int bh = b * Hn + (int)blockIdx.z;
          short* dst = (short*)(n < 64 ? C0 : C1);
          dst[((size_t)bh * Tn + t) * 64 + (n & 63)] = f2bf(val);
        } else {
          ((float*)C0)[(size_t)m * N + n] = val;
        }
      }
    }
  }
}

// ---------------------------------------------------------------------------
// MFMA flash attention v14 = v9 with rg-OUTER restructure (VGPR squeeze):
// QK->softmax->PV per row-group so only sa[4] (16 regs) is transient instead
// of sa[2][4] (32). lp[2][4]->lp[2] (tree-add, -6 regs; epilogue verified in
// r8). Cost: K-frag ds_reads 8->16/iter (conflict-free, ~negligible). Goal:
// VGPR 72 -> <=64 => occupancy 2->3 blocks/CU (m69: steps at 64/128).
// Everything else identical to v9 (verified 91.3 us).
// ---------------------------------------------------------------------------
__constant__ unsigned char ORD6[12] = {12, 30, 31, 26, 27, 8,
                                       22, 23, 18, 19, 4, 0};
#define PP 72
__global__ __launch_bounds__(512) void atn14(
    const short* __restrict__ Qg, const short* __restrict__ Kg,
    const short* __restrict__ VTg, short* __restrict__ Yb,
    short* __restrict__ Opart, float* __restrict__ Lpart) {
  __shared__ short Ks[2][64 * 64];
  __shared__ short Vt[2][64 * 64];
  __shared__ short Ps[8 * 16 * PP];

  const int tid = threadIdx.x;
  const int wave = tid >> 6, lane = tid & 63;
  const int l16 = lane & 15, quad = lane >> 4;
  const unsigned v = ORD6[blockIdx.y];
  const int qt = v >> 2, split = (v >> 1) & 1, half = v & 1;
  const int bh = blockIdx.x;
  const int wtrow = qt * 256 + wave * 32;
  const size_t kb = (size_t)bh * Tn * 64;
  const size_t vb = (size_t)bh * 64 * Tn;
  const int j0 = split ? half * (2 * qt + 2) : 0;
  const int jn = split ? (2 * qt + 2) : (4 * qt + 4);

  // Q fragments: 2 row-groups x 2 k-steps
  bf16x8 qf[2][2];
#pragma unroll
  for (int rg = 0; rg < 2; ++rg)
#pragma unroll
    for (int s = 0; s < 2; ++s)
      qf[rg][s] = *(const bf16x8*)(Qg + kb +
          (size_t)(wtrow + rg * 16 + l16) * 64 + s * 32 + quad * 8);

  f32x4 o[2][4];
#pragma unroll
  for (int rg = 0; rg < 2; ++rg)
#pragma unroll
    for (int dt = 0; dt < 4; ++dt) o[rg][dt] = f32x4{0.f, 0.f, 0.f, 0.f};
  float lp[2] = {0.f, 0.f};  // per-lane row-sum partials for q = l16

  // staging: 512 threads x 16B = one 64x64 bf16 tile per buffer per issue
  const int srow = tid >> 3;                  // 0..63
  const int sseg = (tid & 7) ^ (srow & 7);    // XOR chunk swizzle
#define STAGE7(buf, j)                                                        \
  {                                                                           \
    gld16(Kg + kb + (size_t)((j) * 64 + srow) * 64 + sseg * 8,                \
          &Ks[buf][tid * 8]);                                                 \
    gld16(VTg + vb + (size_t)srow * Tn + (j) * 64 + sseg * 8,                 \
          &Vt[buf][tid * 8]);                                                 \
  }

  STAGE7(0, j0);
  short* pw = &Ps[wave * 16 * PP];
  const int xs = l16 & 7;

  for (int jj = 0; jj < jn; ++jj) {
    const int j = j0 + jj;
    const int cb = jj & 1;
    __syncthreads();  // buf[cb] staged; all waves done reading buf[cb^1]
    if (jj + 1 < jn) STAGE7(cb ^ 1, j + 1);  // full-iteration prefetch window

    const bool act1 = (j * 64 <= wtrow + 31);
    const bool act0 = (j * 64 <= wtrow + 15);
    if (!act1) continue;  // wave still hits next barrier

#pragma unroll
    for (int rg = 0; rg < 2; ++rg) {
      if (rg == 0 && !act0) continue;
      // QK^T swapped for THIS rg only: sa[ct], lane q=l16, k=quad*4+r
      f32x4 sa[4];
      __builtin_amdgcn_s_setprio(1);
#pragma unroll
      for (int ct = 0; ct < 4; ++ct) {
        bf16x8 k0 = *(const bf16x8*)&Ks[cb][(ct * 16 + l16) * 64 + ((0 + quad) ^ xs) * 8];
        bf16x8 k1 = *(const bf16x8*)&Ks[cb][(ct * 16 + l16) * 64 + ((4 + quad) ^ xs) * 8];
        f32x4 t = f32x4{0.f, 0.f, 0.f, 0.f};
        t = __builtin_amdgcn_mfma_f32_16x16x32_bf16(k0, qf[rg][0], t, 0, 0, 0);
        t = __builtin_amdgcn_mfma_f32_16x16x32_bf16(k1, qf[rg][1], t, 0, 0, 0);
        sa[ct] = t;
      }
      __builtin_amdgcn_s_setprio(0);

      const int rbase = wtrow + rg * 16;
      const int trow = rbase + l16;  // this lane's q row
      const bool full = (j * 64 + 63 <= rbase);
      float lacc = 0.f;
#pragma unroll
      for (int ct = 0; ct < 4; ++ct) {
        const int ubase = j * 64 + ct * 16 + quad * 4;
        bf16x4 pk;
        float e0, e1, e2, e3;
        if (full) {
          e0 = fexp2(sa[ct][0]); e1 = fexp2(sa[ct][1]);
          e2 = fexp2(sa[ct][2]); e3 = fexp2(sa[ct][3]);
        } else {
          e0 = (ubase + 0 <= trow) ? fexp2(sa[ct][0]) : 0.f;
          e1 = (ubase + 1 <= trow) ? fexp2(sa[ct][1]) : 0.f;
          e2 = (ubase + 2 <= trow) ? fexp2(sa[ct][2]) : 0.f;
          e3 = (ubase + 3 <= trow) ? fexp2(sa[ct][3]) : 0.f;
        }
        pk[0] = f2bf(e0); pk[1] = f2bf(e1); pk[2] = f2bf(e2); pk[3] = f2bf(e3);
        lacc += (e0 + e1) + (e2 + e3);
        *(bf16x4*)&pw[l16 * PP + ct * 16 + quad * 4] = pk;  // 8B store
      }
      lp[rg] += lacc;
      bf16x8 pf0 = *(const bf16x8*)&pw[l16 * PP + quad * 8];
      bf16x8 pf1 = *(const bf16x8*)&pw[l16 * PP + 32 + quad * 8];
      // PV: load V^T frags per-dt (short live range)
      __builtin_amdgcn_s_setprio(1);
#pragma unroll
      for (int dt = 0; dt < 4; ++dt) {
        bf16x8 v0 = *(const bf16x8*)&Vt[cb][(dt * 16 + l16) * 64 + ((0 + quad) ^ xs) * 8];
        bf16x8 v1 = *(const bf16x8*)&Vt[cb][(dt * 16 + l16) * 64 + ((4 + quad) ^ xs) * 8];
        o[rg][dt] = __builtin_amdgcn_mfma_f32_16x16x32_bf16(pf0, v0, o[rg][dt], 0, 0, 0);
        o[rg][dt] = __builtin_amdgcn_mfma_f32_16x16x32_bf16(pf1, v1, o[rg][dt], 0, 0, 0);
      }
      __builtin_amdgcn_s_setprio(0);
    }
  }

  const int row = lane >> 2, cseg = lane & 3;
  if (!split) {
    const int b = bh >> 4, h = bh & 15;
#pragma unroll
    for (int rg = 0; rg < 2; ++rg) {
      // full row-sum for q=l16: sum partials across quads
      float lfull = lp[rg];
      lfull += __shfl_xor(lfull, 16);
      lfull += __shfl_xor(lfull, 32);
      float invf = 1.f / lfull;  // valid per lane for q = l16
      float inv[4];
#pragma unroll
      for (int r = 0; r < 4; ++r) inv[r] = __shfl(invf, quad * 4 + r);
#pragma unroll
      for (int dt = 0; dt < 4; ++dt)
#pragma unroll
        for (int r = 0; r < 4; ++r)
          pw[(quad * 4 + r) * PP + dt * 16 + l16] = f2bf(o[rg][dt][r] * inv[r]);
      bf16x8 y0 = *(const bf16x8*)&pw[row * PP + cseg * 16];
      bf16x8 y1 = *(const bf16x8*)&pw[row * PP + cseg * 16 + 8];
      short* dst = Yb + ((size_t)(b * Tn + wtrow + rg * 16 + row)) * Cn +
                   h * 64 + cseg * 16;
      *(bf16x8*)dst = y0;
      *(bf16x8*)(dst + 8) = y1;
    }
  } else {
    // unnormalized additive partials
    const int slot = (bh * 4 + (qt - 4)) * 2 + half;
#pragma unroll
    for (int rg = 0; rg < 2; ++rg) {
      float lfull = lp[rg];
      lfull += __shfl_xor(lfull, 16);
      lfull += __shfl_xor(lfull, 32);
#pragma unroll
      for (int dt = 0; dt < 4; ++dt)
#pragma unroll
        for (int r = 0; r < 4; ++r)
          pw[(quad * 4 + r) * PP + dt * 16 + l16] = f2bf(o[rg][dt][r]);
      bf16x8 y0 = *(const bf16x8*)&pw[row * PP + cseg * 16];
      bf16x8 y1 = *(const bf16x8*)&pw[row * PP + cseg * 16 + 8];
      const int rrow = wave * 32 + rg * 16 + row;
      short* dst = Opart + ((size_t)slot * 256 + rrow) * 64 + cseg * 16;
      *(bf16x8*)dst = y0;
      *(bf16x8*)(dst + 8) = y1;
      if (quad == 0) Lpart[slot * 256 + wave * 32 + rg * 16 + l16] = lfull;
    }
  }
}

// ---------------------------------------------------------------------------
// combine: for qt 4..7 (rows 1024..2047), y = (Oa + Ob) / (la + lb) -> yb
// ---------------------------------------------------------------------------
__global__ __launch_bounds__(256) void combine_k(
    const short* __restrict__ Opart, const float* __restrict__ Lpart,
    short* __restrict__ Yb) {
  int gid = blockIdx.x * 256 + threadIdx.x;  // 524288
  int seg = gid & 7, row = (gid >> 3) & 255, qtr = (gid >> 11) & 3,
      bh = gid >> 13;
  int slotA = (bh * 4 + qtr) * 2, slotB = slotA + 1;
  float la = Lpart[slotA * 256 + row], lb = Lpart[slotB * 256 + row];
  float inv = 1.f / (la + lb);
  bf16x8 a = *(const bf16x8*)(Opart + ((size_t)slotA * 256 + row) * 64 + seg * 8);
  bf16x8 b = *(const bf16x8*)(Opart + ((size_t)slotB * 256 + row) * 64 + seg * 8);
  bf16x8 y;
#pragma unroll
  for (int i = 0; i < 8; ++i) y[i] = f2bf((bf2f(a[i]) + bf2f(b[i])) * inv);
  int t = (qtr + 4) * 256 + row, bb = bh >> 4, h = bh & 15;
  *(bf16x8*)(Yb + ((size_t)(bb * Tn + t)) * Cn + h * 64 + seg * 8) = y;
}

// ---------------------------------------------------------------------------
extern "C" void kernel_launch(void* const* d_in, const int* in_sizes, int n_in,
                              void* d_out, int out_size, void* d_ws,
                              size_t ws_size, hipStream_t stream) {
  const float* x        = (const float*)d_in[0];
  const float* basis_w  = (const float*)d_in[1];
  const float* u_factor = (const float*)d_in[2];
  const float* v_factor = (const float*)d_in[3];
  const float* v_proj_w = (const float*)d_in[4];
  const float* v_proj_b = (const float*)d_in[5];
  const float* o_proj_w = (const float*)d_in[6];
  const float* o_proj_b = (const float*)d_in[7];
  float* out = (float*)d_out;

  char* ws = (char*)d_ws;
  const size_t NX = (size_t)Bn * Tn * Cn;          // 8,388,608
  short* xb      = (short*)ws; ws += NX * 2;       // contig with next 3 (cvtall)
  short* bwb     = (short*)ws; ws += (size_t)Rn * Cn * 2;  // basis | vproj
  short* vpb     = (short*)ws; ws += (size_t)Cn * Cn * 2;  //   contiguous !
  short* opb     = (short*)ws; ws += (size_t)Cn * Cn * 2;
  short* uvb     = (short*)ws; ws += (size_t)Hn * 128 * Rn * 2;
  short* latentb = (short*)ws; ws += (size_t)Bn * Tn * Rn * 2;
  short* Qb      = (short*)ws; ws += NX * 2;       // [bh,T,64]
  short* Kb      = (short*)ws; ws += NX * 2;
  short* VTb     = (short*)ws; ws += NX * 2;       // [bh,64,T]
  short* yb      = (short*)ws; ws += NX * 2;       // [8192,1024]
  short* Opart   = (short*)ws; ws += (size_t)512 * 256 * 64 * 2;  // 16.8 MB
  float* Lpart   = (float*)ws;                     // 512*256 f32
  (void)vpb;

  dim3 blk(256);
  cvtall<<<dim3(5504), blk, 0, stream>>>(x, basis_w, v_proj_w, o_proj_w,
                                         u_factor, v_factor, xb, uvb);

  // fused latent|V: [8192,1280] = xb @ [basis_w;v_proj_w]^T
  //   n<256 -> latentb (bf16 [8192,256]); n>=256 -> V^T [bh,64,T] + bias
  gemm_mfma<5, 1><<<dim3(64, 10, 1), blk, 0, stream>>>(
      xb, bwb, v_proj_b, latentb, VTb, 8192, 1280, 1024, 0);
  // q|k = latent @ uv[h]^T : per-head split into Qb, Kb  (r10 form)
  gemm_mfma<1, 0><<<dim3(64, 1, 16), blk, 0, stream>>>(
      latentb, uvb, nullptr, Qb, Kb, 8192, 128, 256, 128 * 256);
  // attention (256-row blocks, dbuf staging, split-key) -> yb + partials
  atn14<<<dim3(64, 12), dim3(512), 0, stream>>>(Qb, Kb, VTb, yb, Opart, Lpart);
  combine_k<<<dim3(2048), blk, 0, stream>>>(Opart, Lpart, yb);
  // out = yb @ o_proj^T + b : fp32
  gemm_mfma<3, 1><<<dim3(64, 8, 1), blk, 0, stream>>>(
      yb, opb, o_proj_b, out, nullptr, 8192, 1024, 1024, 0);
}